// Round 18
// baseline (435.496 us; speedup 1.0000x reference)
//
#include <hip/hip_runtime.h>
#include <math.h>

#define NN 25000
#define NE 400000
#define NB_ (NE / 64)   // 6250 fused blocks
#define WSP 204         // wS row pitch in shorts: 4-row groups -> disjoint bank ranges

static constexpr float C_S_ = 0.3826834323650898f;   // sin(pi/8)
static constexpr float C_X_ = 0.9238795325112867f;   // cos(pi/8)
static constexpr float Q_   = 0.25f;                 // 1/sqrt(16)
static constexpr float Q_S3 = 0.25f * 0.5773502691896258f; // Q / sqrt(3)

typedef __attribute__((ext_vector_type(8))) short bf16x8;
typedef __attribute__((ext_vector_type(4))) float f32x4;

__device__ inline unsigned short f2bf(float f) {
    union { float f; unsigned u; } v; v.f = f;
    unsigned r = v.u + 0x7fffu + ((v.u >> 16) & 1u);   // RNE
    return (unsigned short)(r >> 16);
}
__device__ inline float bf2f(unsigned short s) {
    union { unsigned u; float f; } v; v.u = ((unsigned)s) << 16;
    return v.f;
}

// ---------------- K0: pack weights (all bf16 MFMA B-fragments) -----------------
__global__ void k_pack(const float* __restrict__ Wfc2,
                       const float* __restrict__ Wsa, const float* __restrict__ Wsc,
                       const float* __restrict__ W1sa, const float* __restrict__ W1sc,
                       const float* __restrict__ Wva, const float* __restrict__ Wvc,
                       const float* __restrict__ W1va, const float* __restrict__ W1vc,
                       const float* __restrict__ Wl2sa, const float* __restrict__ Wl2sc,
                       const float* __restrict__ Wl2va, const float* __restrict__ Wl2vc,
                       const float* __restrict__ Wl3s, const float* __restrict__ Wl3v,
                       unsigned short* __restrict__ Wfragb,
                       unsigned short* __restrict__ WsabF, unsigned short* __restrict__ WvabF,
                       unsigned short* __restrict__ Wl3sF, unsigned short* __restrict__ Wl3vF,
                       unsigned short* __restrict__ WscF, unsigned short* __restrict__ W1sF,
                       unsigned short* __restrict__ WvcF, unsigned short* __restrict__ W1vF)
{
    int t = blockIdx.x * blockDim.x + threadIdx.x;
    if (t < 24576) {
        int i = t & 7, l = (t >> 3) & 63, ks = (t >> 9) & 3, nt = t >> 11;
        int k = ks * 32 + ((l >> 4) << 3) + i;
        int n = nt * 16 + (l & 15);
        Wfragb[t] = (k < 100) ? f2bf(Wfc2[k * 192 + n]) : (unsigned short)0;
        return;
    }
    t -= 24576;
    if (t < 18432) {
        int i = t & 7, l = (t >> 3) & 63, rem = t >> 9;
        int ks = rem % 6, nt = rem / 6;
        int k = ks * 32 + ((l >> 4) << 3) + i;
        int n = nt * 16 + (l & 15);
        WsabF[t] = f2bf(k < 96 ? Wl2sa[k * 96 + n] : Wl2sc[(k - 96) * 96 + n]);
        return;
    }
    t -= 18432;
    if (t < 18432) {
        int i = t & 7, l = (t >> 3) & 63, rem = t >> 9;
        int ks = rem % 6, nt = rem / 6;
        int k = ks * 32 + ((l >> 4) << 3) + i;
        int n = nt * 16 + (l & 15);
        WvabF[t] = f2bf(k < 96 ? Wl2va[k * 96 + n] : Wl2vc[(k - 96) * 96 + n]);
        return;
    }
    t -= 18432;
    if (t < 6144) {
        int i = t & 7, l = (t >> 3) & 63, rem = t >> 9;
        int ks = rem % 3, nt = rem / 3;
        int k = ks * 32 + ((l >> 4) << 3) + i;
        int n = nt * 16 + (l & 15);
        Wl3sF[t] = f2bf(Wl3s[k * 64 + n]);
        return;
    }
    t -= 6144;
    if (t < 3072) {
        int i = t & 7, l = (t >> 3) & 63, rem = t >> 9;
        int ks = rem % 3, nt = rem / 3;
        int k = ks * 32 + ((l >> 4) << 3) + i;
        int n = nt * 16 + (l & 15);
        Wl3vF[t] = f2bf(Wl3v[k * 32 + n]);
        return;
    }
    t -= 3072;
    if (t < 8192) {
        int i = t & 7, l = (t >> 3) & 63, rem = t >> 9;
        int ks = rem & 3, nt = rem >> 2;
        int k = ks * 32 + ((l >> 4) << 3) + i;
        int n = nt * 16 + (l & 15);
        WscF[t] = f2bf(k < 64 ? Wsa[k * 64 + n] : Wsc[(k - 64) * 64 + n]);
        return;
    }
    t -= 8192;
    if (t < 8192) {
        int i = t & 7, l = (t >> 3) & 63, rem = t >> 9;
        int ks = rem & 3, nt = rem >> 2;
        int k = ks * 32 + ((l >> 4) << 3) + i;
        int n = nt * 16 + (l & 15);
        W1sF[t] = f2bf(k < 64 ? W1sa[k * 64 + n] : W1sc[(k - 64) * 64 + n]);
        return;
    }
    t -= 8192;
    if (t < 2048) {
        int i = t & 7, l = (t >> 3) & 63, rem = t >> 9;
        int ks = rem & 1, nt = rem >> 1;
        int k = ks * 32 + ((l >> 4) << 3) + i;
        int n = nt * 16 + (l & 15);
        WvcF[t] = f2bf(k < 32 ? Wva[k * 32 + n] : Wvc[(k - 32) * 32 + n]);
        return;
    }
    t -= 2048;
    if (t < 2048) {
        int i = t & 7, l = (t >> 3) & 63, rem = t >> 9;
        int ks = rem & 1, nt = rem >> 1;
        int k = ks * 32 + ((l >> 4) << 3) + i;
        int n = nt * 16 + (l & 15);
        W1vF[t] = f2bf(k < 32 ? W1va[k * 32 + n] : W1vc[(k - 32) * 32 + n]);
        return;
    }
}

// ---------------- K1: node prep via MFMA ---------------------------------------
__global__ __launch_bounds__(256, 2) void k_np_mfma(
    const float* __restrict__ ni, const float* __restrict__ attr, const float* __restrict__ cattr,
    const unsigned short* __restrict__ WscF, const unsigned short* __restrict__ W1sF,
    const unsigned short* __restrict__ WvcF, const unsigned short* __restrict__ W1vF,
    float* __restrict__ x1, float* __restrict__ out)
{
    __shared__ char A1[64 * 256];
    int slot = blockIdx.y, cc = slot - 1;
    int n0 = blockIdx.x * 64;
    int tid = threadIdx.x, lane = tid & 63, w = tid >> 6;

    if (slot == 0) {
        for (int idx = tid; idx < 64 * 64; idx += 256) {
            int r = idx >> 6, k = idx & 63;
            int n = n0 + r;
            float a = 0.f, cv = 0.f, val = 0.f;
            if (n < NN) { a = attr[n]; cv = cattr[n]; val = ni[(size_t)n * 160 + k]; }
            int sw = (r & 7) << 4;
            *(unsigned short*)(A1 + r * 256 + ((2 * k) ^ sw))       = f2bf(a  * val);
            *(unsigned short*)(A1 + r * 256 + ((128 + 2 * k) ^ sw)) = f2bf(cv * val);
        }
    } else {
        for (int idx = tid; idx < 64 * 32; idx += 256) {
            int r = idx >> 5, u = idx & 31;
            int n = n0 + r;
            float a = 0.f, cv = 0.f, val = 0.f;
            if (n < NN) { a = attr[n]; cv = cattr[n]; val = ni[(size_t)n * 160 + 64 + 3 * u + cc]; }
            int sw = (r & 7) << 4;
            *(unsigned short*)(A1 + r * 128 + ((2 * u) ^ sw))      = f2bf(a  * val);
            *(unsigned short*)(A1 + r * 128 + ((64 + 2 * u) ^ sw)) = f2bf(cv * val);
        }
    }
    __syncthreads();

    int arow = w * 16 + (lane & 15);
    int asw  = (arow & 7) << 4;

    if (slot == 0) {
        f32x4 accS[4], accX[4];
        #pragma unroll
        for (int nt = 0; nt < 4; ++nt) { accS[nt] = (f32x4)0.f; accX[nt] = (f32x4)0.f; }
        #pragma unroll
        for (int ks = 0; ks < 4; ++ks) {
            int kb = ks * 64 + ((lane >> 4) << 4);
            bf16x8 af = *(const bf16x8*)(A1 + arow * 256 + (kb ^ asw));
            #pragma unroll
            for (int nt = 0; nt < 4; ++nt) {
                bf16x8 b1 = *(const bf16x8*)(WscF + (size_t)(((nt * 4 + ks) * 64) + lane) * 8);
                bf16x8 b2 = *(const bf16x8*)(W1sF + (size_t)(((nt * 4 + ks) * 64) + lane) * 8);
                accS[nt] = __builtin_amdgcn_mfma_f32_16x16x32_bf16(af, b1, accS[nt], 0, 0, 0);
                accX[nt] = __builtin_amdgcn_mfma_f32_16x16x32_bf16(af, b2, accX[nt], 0, 0, 0);
            }
        }
        #pragma unroll
        for (int r = 0; r < 4; ++r) {
            int n = n0 + w * 16 + ((lane >> 4) << 2) + r;
            if (n >= NN) continue;
            #pragma unroll
            for (int nt = 0; nt < 4; ++nt) {
                int col = nt * 16 + (lane & 15);
                out[(size_t)n * 160 + col] = C_S_ * accS[nt][r];
                x1[(size_t)n * 160 + col]  = accX[nt][r];
            }
        }
    } else {
        f32x4 accS[2], accX[2];
        #pragma unroll
        for (int nt = 0; nt < 2; ++nt) { accS[nt] = (f32x4)0.f; accX[nt] = (f32x4)0.f; }
        #pragma unroll
        for (int ks = 0; ks < 2; ++ks) {
            int kb = ks * 64 + ((lane >> 4) << 4);
            bf16x8 af = *(const bf16x8*)(A1 + arow * 128 + (kb ^ asw));
            #pragma unroll
            for (int nt = 0; nt < 2; ++nt) {
                bf16x8 b1 = *(const bf16x8*)(WvcF + (size_t)(((nt * 2 + ks) * 64) + lane) * 8);
                bf16x8 b2 = *(const bf16x8*)(W1vF + (size_t)(((nt * 2 + ks) * 64) + lane) * 8);
                accS[nt] = __builtin_amdgcn_mfma_f32_16x16x32_bf16(af, b1, accS[nt], 0, 0, 0);
                accX[nt] = __builtin_amdgcn_mfma_f32_16x16x32_bf16(af, b2, accX[nt], 0, 0, 0);
            }
        }
        #pragma unroll
        for (int r = 0; r < 4; ++r) {
            int n = n0 + w * 16 + ((lane >> 4) << 2) + r;
            if (n >= NN) continue;
            #pragma unroll
            for (int nt = 0; nt < 2; ++nt) {
                int o = nt * 16 + (lane & 15);
                int d = 64 + 3 * o + cc;
                out[(size_t)n * 160 + d] = C_S_ * accS[nt][r];
                x1[(size_t)n * 160 + d]  = accX[nt][r];
            }
        }
    }
}

// ---------------- sort: histogram ---------------------------------------------
__global__ __launch_bounds__(256) void k_hist(const int* __restrict__ edst, int* __restrict__ cnt) {
    int e = blockIdx.x * blockDim.x + threadIdx.x;
    if (e >= NE) return;
    atomicAdd(&cnt[edst[e]], 1);
}

// ---------------- sort: single-block exclusive scan over NN counts ------------
__global__ __launch_bounds__(1024) void k_scan(const int* __restrict__ cnt,
                                               int* __restrict__ start, int* __restrict__ cursor) {
    __shared__ int wsum[16];
    __shared__ int carry_s;
    int lane = threadIdx.x & 63, wid = threadIdx.x >> 6;
    if (threadIdx.x == 0) carry_s = 0;
    __syncthreads();
    for (int base = 0; base < NN; base += 1024) {
        int i = base + threadIdx.x;
        int v = (i < NN) ? cnt[i] : 0;
        int x = v;
        #pragma unroll
        for (int off = 1; off < 64; off <<= 1) {
            int y = __shfl_up(x, off, 64);
            if (lane >= off) x += y;
        }
        if (lane == 63) wsum[wid] = x;
        __syncthreads();
        if (wid == 0 && lane < 16) {
            int s = wsum[lane];
            #pragma unroll
            for (int off = 1; off < 16; off <<= 1) {
                int y = __shfl_up(s, off, 64);
                if (lane >= off) s += y;
            }
            wsum[lane] = s;
        }
        __syncthreads();
        int woff = (wid > 0) ? wsum[wid - 1] : 0;
        int excl = x - v + woff + carry_s;
        if (i < NN) { start[i] = excl; cursor[i] = excl; }
        __syncthreads();
        if (threadIdx.x == 1023) carry_s += wsum[15];
        __syncthreads();
    }
    if (threadIdx.x == 0) start[NN] = NE;
}

// ---------------- sort: scatter — permute ele/esrc/eattr/ndst into sorted order
__global__ __launch_bounds__(256) void k_scatter(const int* __restrict__ edst,
                                                 const int* __restrict__ esrc,
                                                 const float* __restrict__ eattr,
                                                 const float* __restrict__ ele,
                                                 int* __restrict__ cursor,
                                                 int* __restrict__ esrc_s,
                                                 int* __restrict__ ndst_s,
                                                 float4* __restrict__ eattr_s,
                                                 float* __restrict__ ele_s) {
    int e = blockIdx.x * blockDim.x + threadIdx.x;
    if (e >= NE) return;
    int dst = edst[e];
    int p = atomicAdd(&cursor[dst], 1);
    esrc_s[p]  = esrc[e];
    ndst_s[p]  = dst;
    eattr_s[p] = *(const float4*)(eattr + (size_t)e * 4);
    #pragma unroll
    for (int k = 0; k < 10; ++k) ele_s[(size_t)p * 10 + k] = ele[(size_t)e * 10 + k];
}

// ---------------- K2: FUSED edge MLP + MFMA + tensor-product aggregation -------
// Block = 64 sorted edges, 384 threads (6 waves). hA/wS share LDS.
// Phase 5 v4: BOTH half-blocks aggregate (half 0 -> edges 0..31, half 1 ->
// edges 32..63) = 2x gather TLP; midpoint-spanning node merged via cross[] LDS.
__global__ __launch_bounds__(384, 8) void k_fused(
    const float* __restrict__ ele_s, const int* __restrict__ esrc_s,
    const int* __restrict__ ndst_s, const float4* __restrict__ eattr_s,
    const int* __restrict__ start,
    const float* __restrict__ Wfc1, const unsigned short* __restrict__ Wfragb,
    const float* __restrict__ x1, float* __restrict__ agg,
    float* __restrict__ partials, int* __restrict__ pnid)
{
    __shared__ float  els[640];
    __shared__ int    nid[64];
    __shared__ unsigned long long bmask_s;
    __shared__ float  cross[2][384];
    __shared__ char   uS[64 * (WSP * 2)];    // phase2-3: hA [64][256B]; phase4-5: wS [64][WSP shorts]
    char* hA = uS;
    unsigned short* wS = (unsigned short*)uS;

    int tid = threadIdx.x, lane = tid & 63, w = tid >> 6;
    int b = blockIdx.x;
    int base = b * 64;

    // phase 1: stage per-edge data consumed per-lane (els) / per-flush (nid)
    for (int idx = tid; idx < 640; idx += 384) els[idx] = ele_s[(size_t)base * 10 + idx];
    if (tid < 64) nid[tid] = ndst_s[base + tid];
    if (tid == 0) { pnid[b * 2 + 0] = -1; pnid[b * 2 + 1] = -1; }
    __syncthreads();

    // phase 2: h = silu(el @ Wfc1) -> hA (row-major map: conflict-free writes)
    #pragma unroll 1
    for (int t2 = tid; t2 < 6400; t2 += 384) {
        int e_loc = t2 / 100;
        int j = t2 - e_loc * 100;
        const float* elp = els + e_loc * 10;
        float acc = 0.f;
        #pragma unroll
        for (int k = 0; k < 10; ++k) acc += elp[k] * Wfc1[k * 100 + j];
        float hv = acc / (1.f + __expf(-acc));
        *(unsigned short*)(hA + e_loc * 256 + ((j * 2) ^ ((e_loc & 7) << 4))) = f2bf(hv);
    }
    for (int idx = tid; idx < 64 * 28; idx += 384) {
        int e_loc = idx / 28;
        int col2 = (100 + (idx - e_loc * 28)) * 2;
        *(unsigned short*)(hA + e_loc * 256 + (col2 ^ ((e_loc & 7) << 4))) = 0;
    }
    __syncthreads();

    // phase 3: MFMA — 6 waves x 2 n-tiles x 4 mt x 4 ks
    bf16x8 bfr[2][4];
    #pragma unroll
    for (int nt2 = 0; nt2 < 2; ++nt2)
        #pragma unroll
        for (int ks = 0; ks < 4; ++ks)
            bfr[nt2][ks] = ((const bf16x8*)Wfragb)[(((w * 2 + nt2) * 4) + ks) * 64 + lane];

    f32x4 acc[4][2];
    #pragma unroll
    for (int mt = 0; mt < 4; ++mt)
        #pragma unroll
        for (int nt2 = 0; nt2 < 2; ++nt2)
            acc[mt][nt2] = (f32x4)0.f;

    #pragma unroll
    for (int mt = 0; mt < 4; ++mt) {
        int row = mt * 16 + (lane & 15);
        #pragma unroll
        for (int ks = 0; ks < 4; ++ks) {
            int kb = ks * 64 + ((lane >> 4) << 4);
            bf16x8 a = *(const bf16x8*)(hA + row * 256 + (kb ^ ((row & 7) << 4)));
            #pragma unroll
            for (int nt2 = 0; nt2 < 2; ++nt2)
                acc[mt][nt2] = __builtin_amdgcn_mfma_f32_16x16x32_bf16(a, bfr[nt2][ks], acc[mt][nt2], 0, 0, 0);
        }
    }
    __syncthreads();   // hA dead; wS aliases it — all reads must complete first

    // phase 4: weights -> LDS, pitch WSP=204 (4-row groups hit disjoint banks)
    #pragma unroll
    for (int mt = 0; mt < 4; ++mt) {
        #pragma unroll
        for (int nt2 = 0; nt2 < 2; ++nt2) {
            int col = (w * 2 + nt2) * 16 + (lane & 15);
            #pragma unroll
            for (int r = 0; r < 4; ++r) {
                int row = mt * 16 + ((lane >> 4) << 2) + r;
                wS[row * WSP + col] = f2bf(acc[mt][nt2][r]);
            }
        }
    }
    // segment-boundary bitmask (wave 0); published by the same barrier as wS
    if (tid < 64) {
        bool lastb = (tid == 63) || (nid[tid + 1] != nid[tid]);
        unsigned long long m = __ballot(lastb);
        if (tid == 0) bmask_s = m;
    }
    __syncthreads();   // RAW fence for wS + bmask_s (R9 lesson)

    // phase 5 v4: both halves aggregate 32 edges each.
    {
        int t = tid % 192;
        int half = tid / 192;
        int role, widx, gidx, dcol;
        float scale;
        if (t < 64)       { role = 0; widx = t;       gidx = t;           dcol = t;           scale = Q_;   }
        else if (t < 96)  { int o = t - 64;  role = 1; widx = 160 + o; gidx = 64 + 3 * o; dcol = 64 + o;      scale = Q_S3; }
        else if (t < 160) { int u = t - 96;  role = 2; widx = 64 + u;  gidx = u;          dcol = 96 + 3 * u;  scale = Q_;   }
        else              { int o = t - 160; role = 3; widx = 128 + o; gidx = 64 + 3 * o; dcol = 288 + 3 * o; scale = Q_;   }
        bool needs3g = (role == 1) || (role == 3);
        bool crossing = (nid[31] == nid[32]);

        unsigned long long bm = bmask_s;
        float a0 = 0.f, a1 = 0.f, a2 = 0.f;
        int e_lo = half * 32;
        int curNode = nid[e_lo];
        bool firstFlush = true;
        #pragma unroll 1
        for (int i0 = e_lo; i0 < e_lo + 32; i0 += 4) {
            float g0[4], g1[4], g2[4];
            #pragma unroll
            for (int q = 0; q < 4; ++q) {
                const float* g = x1 + (size_t)esrc_s[base + i0 + q] * 160;
                g0[q] = g[gidx];
                if (needs3g) { g1[q] = g[gidx + 1]; g2[q] = g[gidx + 2]; }
            }
            #pragma unroll
            for (int q = 0; q < 4; ++q) {
                int i = i0 + q;
                float4 ea = eattr_s[base + i];
                float wv = bf2f(wS[i * WSP + widx]);
                if (role == 0)      a0 += wv * g0[q] * ea.x;
                else if (role == 1) a0 += wv * (g0[q] * ea.y + g1[q] * ea.z + g2[q] * ea.w);
                else if (role == 2) { float p = wv * g0[q]; a0 += p * ea.y; a1 += p * ea.z; a2 += p * ea.w; }
                else                { float p = wv * ea.x;  a0 += p * g0[q]; a1 += p * g1[q]; a2 += p * g2[q]; }
                if ((bm >> i) & 1ull) {
                    if (crossing && half == 1 && firstFlush) {
                        // continuation of the midpoint-spanning node
                        cross[1][dcol] = a0 * scale;
                        if (role >= 2) { cross[1][dcol + 1] = a1 * scale; cross[1][dcol + 2] = a2 * scale; }
                    } else {
                        int n = curNode;
                        int s0n = start[n], s1n = start[n + 1];
                        bool interior = (s0n >= base) && (s1n <= base + 64);
                        float* dstp;
                        if (interior) {
                            dstp = agg + (size_t)n * 384;
                        } else if (n == nid[0]) {
                            dstp = partials + ((size_t)b * 2 + 0) * 384;
                            if (tid == 0) pnid[b * 2 + 0] = n;
                        } else {
                            dstp = partials + ((size_t)b * 2 + 1) * 384;
                            if (tid == 192) pnid[b * 2 + 1] = n;
                        }
                        dstp[dcol] = a0 * scale;
                        if (role >= 2) { dstp[dcol + 1] = a1 * scale; dstp[dcol + 2] = a2 * scale; }
                    }
                    firstFlush = false;
                    a0 = a1 = a2 = 0.f;
                    if (i < 63) curNode = nid[i + 1];
                }
            }
        }
        if (crossing && half == 0) {
            // open tail of half 0 = first part of the midpoint-spanning node
            cross[0][dcol] = a0 * scale;
            if (role >= 2) { cross[0][dcol + 1] = a1 * scale; cross[0][dcol + 2] = a2 * scale; }
        }
        __syncthreads();
        if (crossing && half == 0) {
            int n = nid[31];
            int s0n = start[n], s1n = start[n + 1];
            bool interior = (s0n >= base) && (s1n <= base + 64);
            float* dstp;
            if (interior) {
                dstp = agg + (size_t)n * 384;
            } else if (n == nid[0]) {
                dstp = partials + ((size_t)b * 2 + 0) * 384;
                if (tid == 0) pnid[b * 2 + 0] = n;
            } else {
                dstp = partials + ((size_t)b * 2 + 1) * 384;
                if (tid == 0) pnid[b * 2 + 1] = n;
            }
            dstp[dcol] = cross[0][dcol] + cross[1][dcol];
            if (role >= 2) {
                dstp[dcol + 1] = cross[0][dcol + 1] + cross[1][dcol + 1];
                dstp[dcol + 2] = cross[0][dcol + 2] + cross[1][dcol + 2];
            }
        }
    }
}

// ---------------- K2c: fixup — sum partials for block-spanning nodes ----------
__global__ __launch_bounds__(256) void k_fixup(
    const int* __restrict__ start, const int* __restrict__ pnid,
    const float* __restrict__ partials, float* __restrict__ agg)
{
    int T = blockIdx.x * blockDim.x + threadIdx.x;
    if (T >= NN * 384) return;
    int n = T / 384, col = T - n * 384;
    int s0 = start[n], s1 = start[n + 1];
    if (s0 == s1) { agg[(size_t)n * 384 + col] = 0.f; return; }
    int b0 = s0 >> 6, b1 = (s1 - 1) >> 6;
    if (b0 == b1) return;   // interior: direct-written by k_fused
    float sum = 0.f;
    for (int b = b0; b <= b1; ++b) {
        if (pnid[2 * b]     == n) sum += partials[((size_t)2 * b)     * 384 + col];
        if (pnid[2 * b + 1] == n) sum += partials[((size_t)2 * b + 1) * 384 + col];
    }
    agg[(size_t)n * 384 + col] = sum;
}

// ---------------- K3: fused l2+l3 double-MFMA ---------------------------------
__global__ __launch_bounds__(256, 2) void k_l23(
    const float* __restrict__ agg, const float* __restrict__ attr,
    const float* __restrict__ cattr, const float* __restrict__ sym,
    const unsigned short* __restrict__ WsabF, const unsigned short* __restrict__ WvabF,
    const unsigned short* __restrict__ Wl3sF, const unsigned short* __restrict__ Wl3vF,
    float* __restrict__ out)
{
    __shared__ char A1[64 * 512];
    __shared__ char A2[64 * 256];

    int slot = blockIdx.y;
    int cc   = slot - 1;
    int n0   = blockIdx.x * 64;
    int tid  = threadIdx.x, lane = tid & 63, w = tid >> 6;

    for (int idx = tid; idx < 64 * 96; idx += 256) {
        int r = idx / 96, km = idx - r * 96;
        int n = n0 + r;
        float a = 0.f, cv = 0.f, val = 0.f;
        if (n < NN) {
            a = attr[n]; cv = cattr[n];
            int src = (slot == 0) ? km : (96 + 3 * km + cc);
            val = agg[(size_t)n * 384 + src];
        }
        int sw = (r & 7) << 4;
        *(unsigned short*)(A1 + r * 512 + ((2 * km) ^ sw))         = f2bf(a  * val);
        *(unsigned short*)(A1 + r * 512 + ((192 + 2 * km) ^ sw))   = f2bf(cv * val);
    }
    __syncthreads();

    const unsigned short* Bf = (slot == 0) ? WsabF : WvabF;
    f32x4 acc1[6];
    #pragma unroll
    for (int nt = 0; nt < 6; ++nt) acc1[nt] = (f32x4)0.f;

    int arow = w * 16 + (lane & 15);
    int asw  = (arow & 7) << 4;
    #pragma unroll
    for (int ks = 0; ks < 6; ++ks) {
        int kb = ks * 64 + ((lane >> 4) << 4);
        bf16x8 af = *(const bf16x8*)(A1 + arow * 512 + (kb ^ asw));
        #pragma unroll
        for (int nt = 0; nt < 6; ++nt) {
            bf16x8 bfrag = *(const bf16x8*)(Bf + (size_t)(((nt * 6 + ks) * 64) + lane) * 8);
            acc1[nt] = __builtin_amdgcn_mfma_f32_16x16x32_bf16(af, bfrag, acc1[nt], 0, 0, 0);
        }
    }

    #pragma unroll
    for (int nt = 0; nt < 6; ++nt) {
        int ncol2 = (nt * 16 + (lane & 15)) * 2;
        #pragma unroll
        for (int r = 0; r < 4; ++r) {
            int row = w * 16 + ((lane >> 4) << 2) + r;
            *(unsigned short*)(A2 + row * 256 + (ncol2 ^ ((row & 7) << 4))) = f2bf(acc1[nt][r]);
        }
    }

    __syncthreads();   // RAW fence (R9 lesson)

    int NT2 = (slot == 0) ? 4 : 2;
    const unsigned short* B2 = (slot == 0) ? Wl3sF : Wl3vF;
    f32x4 acc2[4];
    #pragma unroll
    for (int nt2 = 0; nt2 < 4; ++nt2) acc2[nt2] = (f32x4)0.f;

    #pragma unroll
    for (int ks = 0; ks < 3; ++ks) {
        int kb = ks * 64 + ((lane >> 4) << 4);
        bf16x8 a2 = *(const bf16x8*)(A2 + arow * 256 + (kb ^ ((arow & 7) << 4)));
        #pragma unroll
        for (int nt2 = 0; nt2 < 4; ++nt2) {
            if (nt2 < NT2) {
                bf16x8 b2 = *(const bf16x8*)(B2 + (size_t)(((nt2 * 3 + ks) * 64) + lane) * 8);
                acc2[nt2] = __builtin_amdgcn_mfma_f32_16x16x32_bf16(a2, b2, acc2[nt2], 0, 0, 0);
            }
        }
    }

    #pragma unroll
    for (int r = 0; r < 4; ++r) {
        int n = n0 + w * 16 + ((lane >> 4) << 2) + r;
        if (n >= NN) continue;
        float sv = C_X_ * sym[n];
        #pragma unroll
        for (int nt2 = 0; nt2 < 4; ++nt2) {
            if (nt2 < NT2) {
                int col = nt2 * 16 + (lane & 15);
                int d = (slot == 0) ? col : (64 + 3 * col + cc);
                out[(size_t)n * 160 + d] += sv * acc2[nt2][r];
            }
        }
    }
}

extern "C" void kernel_launch(void* const* d_in, const int* in_sizes, int n_in,
                              void* d_out, int out_size, void* d_ws, size_t ws_size,
                              hipStream_t stream) {
    const float* ni    = (const float*)d_in[0];
    const float* attr  = (const float*)d_in[1];
    const float* cattr = (const float*)d_in[2];
    const float* sym   = (const float*)d_in[3];
    const float* eattr = (const float*)d_in[4];
    const float* ele   = (const float*)d_in[5];
    const int*   esrc  = (const int*)d_in[6];
    const int*   edst  = (const int*)d_in[7];
    const float* Ws_sc_a = (const float*)d_in[8];
    const float* Wv_sc_a = (const float*)d_in[9];
    const float* Ws_sc_c = (const float*)d_in[10];
    const float* Wv_sc_c = (const float*)d_in[11];
    const float* Ws_l1_a = (const float*)d_in[12];
    const float* Wv_l1_a = (const float*)d_in[13];
    const float* Ws_l1_c = (const float*)d_in[14];
    const float* Wv_l1_c = (const float*)d_in[15];
    const float* Wfc1    = (const float*)d_in[16];
    const float* Wfc2    = (const float*)d_in[17];
    const float* Ws_l2_a = (const float*)d_in[18];
    const float* Wv_l2_a = (const float*)d_in[19];
    const float* Ws_l2_c = (const float*)d_in[20];
    const float* Wv_l2_c = (const float*)d_in[21];
    const float* Ws_l3   = (const float*)d_in[22];
    const float* Wv_l3   = (const float*)d_in[23];

    float* out = (float*)d_out;
    float* ws  = (float*)d_ws;
    float* x1  = ws;                          // NN*160 f32
    float* agg = x1 + (size_t)NN * 160;       // NN*384 f32
    unsigned short* Wfragb = (unsigned short*)(agg + (size_t)NN * 384);  // 24576
    unsigned short* WsabF  = Wfragb + 24576;                 // 18432
    unsigned short* WvabF  = WsabF + 18432;                  // 18432
    unsigned short* Wl3sF  = WvabF + 18432;                  // 6144
    unsigned short* Wl3vF  = Wl3sF + 6144;                   // 3072
    unsigned short* WscF   = Wl3vF + 3072;                   // 8192
    unsigned short* W1sF   = WscF + 8192;                    // 8192
    unsigned short* WvcF   = W1sF + 8192;                    // 2048
    unsigned short* W1vF   = WvcF + 2048;                    // 2048
    float4* eattr_s = (float4*)(W1vF + 2048);                // NE float4
    float*  ele_s   = (float*)(eattr_s + NE);                // NE*10 f32
    int* esrc_s  = (int*)(ele_s + (size_t)NE * 10);          // NE
    int* ndst_s  = esrc_s + NE;                              // NE
    int* cnt     = ndst_s + NE;                              // NN
    int* start_  = cnt + NN;                                 // NN+1
    int* cursor  = start_ + NN + 1;                          // NN
    int* pnid    = cursor + NN;                              // 2*NB_
    float* partials = (float*)(pnid + 2 * NB_);              // 2*NB_*384 f32

    size_t need = ((size_t)NN * 160 + (size_t)NN * 384) * 4
                + (size_t)91136 * 2
                + (size_t)NE * 16 + (size_t)NE * 10 * 4
                + ((size_t)NE * 2 + (size_t)NN * 3 + 1 + 2 * NB_) * 4
                + (size_t)2 * NB_ * 384 * 4;
    if (ws_size < need) return;

    k_pack<<<(91136 + 255) / 256, 256, 0, stream>>>(
        Wfc2,
        Ws_sc_a, Ws_sc_c, Ws_l1_a, Ws_l1_c,
        Wv_sc_a, Wv_sc_c, Wv_l1_a, Wv_l1_c,
        Ws_l2_a, Ws_l2_c, Wv_l2_a, Wv_l2_c,
        Ws_l3, Wv_l3,
        Wfragb, WsabF, WvabF, Wl3sF, Wl3vF,
        WscF, W1sF, WvcF, W1vF);

    k_np_mfma<<<dim3((NN + 63) / 64, 4), 256, 0, stream>>>(
        ni, attr, cattr, WscF, W1sF, WvcF, W1vF, x1, out);

    hipMemsetAsync(cnt, 0, (size_t)NN * sizeof(int), stream);
    k_hist<<<(NE + 255) / 256, 256, 0, stream>>>(edst, cnt);
    k_scan<<<1, 1024, 0, stream>>>(cnt, start_, cursor);
    k_scatter<<<(NE + 255) / 256, 256, 0, stream>>>(
        edst, esrc, eattr, ele, cursor, esrc_s, ndst_s, eattr_s, ele_s);

    k_fused<<<NB_, 384, 0, stream>>>(
        ele_s, esrc_s, ndst_s, eattr_s, start_,
        Wfc1, Wfragb, x1, agg, partials, pnid);

    k_fixup<<<(NN * 384 + 255) / 256, 256, 0, stream>>>(
        start_, pnid, partials, agg);

    k_l23<<<dim3((NN + 63) / 64, 4), 256, 0, stream>>>(
        agg, attr, cattr, sym, WsabF, WvabF, Wl3sF, Wl3vF, out);
}

// Round 20
// 353.988 us; speedup vs baseline: 1.2303x; 1.2303x over previous
//
#include <hip/hip_runtime.h>
#include <math.h>

#define NN 25000
#define NE 400000
#define NB_ (NE / 64)   // 6250 fused blocks
#define WSP 204         // wS row pitch in shorts: 4-row groups -> disjoint bank ranges

static constexpr float C_S_ = 0.3826834323650898f;   // sin(pi/8)
static constexpr float C_X_ = 0.9238795325112867f;   // cos(pi/8)
static constexpr float Q_   = 0.25f;                 // 1/sqrt(16)
static constexpr float Q_S3 = 0.25f * 0.5773502691896258f; // Q / sqrt(3)

typedef __attribute__((ext_vector_type(8))) short bf16x8;
typedef __attribute__((ext_vector_type(4))) float f32x4;

__device__ inline unsigned short f2bf(float f) {
    union { float f; unsigned u; } v; v.f = f;
    unsigned r = v.u + 0x7fffu + ((v.u >> 16) & 1u);   // RNE
    return (unsigned short)(r >> 16);
}
__device__ inline float bf2f(unsigned short s) {
    union { unsigned u; float f; } v; v.u = ((unsigned)s) << 16;
    return v.f;
}

// ---------------- K0: pack weights (all bf16 MFMA B-fragments) -----------------
__global__ void k_pack(const float* __restrict__ Wfc2,
                       const float* __restrict__ Wsa, const float* __restrict__ Wsc,
                       const float* __restrict__ W1sa, const float* __restrict__ W1sc,
                       const float* __restrict__ Wva, const float* __restrict__ Wvc,
                       const float* __restrict__ W1va, const float* __restrict__ W1vc,
                       const float* __restrict__ Wl2sa, const float* __restrict__ Wl2sc,
                       const float* __restrict__ Wl2va, const float* __restrict__ Wl2vc,
                       const float* __restrict__ Wl3s, const float* __restrict__ Wl3v,
                       unsigned short* __restrict__ Wfragb,
                       unsigned short* __restrict__ WsabF, unsigned short* __restrict__ WvabF,
                       unsigned short* __restrict__ Wl3sF, unsigned short* __restrict__ Wl3vF,
                       unsigned short* __restrict__ WscF, unsigned short* __restrict__ W1sF,
                       unsigned short* __restrict__ WvcF, unsigned short* __restrict__ W1vF)
{
    int t = blockIdx.x * blockDim.x + threadIdx.x;
    if (t < 24576) {
        int i = t & 7, l = (t >> 3) & 63, ks = (t >> 9) & 3, nt = t >> 11;
        int k = ks * 32 + ((l >> 4) << 3) + i;
        int n = nt * 16 + (l & 15);
        Wfragb[t] = (k < 100) ? f2bf(Wfc2[k * 192 + n]) : (unsigned short)0;
        return;
    }
    t -= 24576;
    if (t < 18432) {
        int i = t & 7, l = (t >> 3) & 63, rem = t >> 9;
        int ks = rem % 6, nt = rem / 6;
        int k = ks * 32 + ((l >> 4) << 3) + i;
        int n = nt * 16 + (l & 15);
        WsabF[t] = f2bf(k < 96 ? Wl2sa[k * 96 + n] : Wl2sc[(k - 96) * 96 + n]);
        return;
    }
    t -= 18432;
    if (t < 18432) {
        int i = t & 7, l = (t >> 3) & 63, rem = t >> 9;
        int ks = rem % 6, nt = rem / 6;
        int k = ks * 32 + ((l >> 4) << 3) + i;
        int n = nt * 16 + (l & 15);
        WvabF[t] = f2bf(k < 96 ? Wl2va[k * 96 + n] : Wl2vc[(k - 96) * 96 + n]);
        return;
    }
    t -= 18432;
    if (t < 6144) {
        int i = t & 7, l = (t >> 3) & 63, rem = t >> 9;
        int ks = rem % 3, nt = rem / 3;
        int k = ks * 32 + ((l >> 4) << 3) + i;
        int n = nt * 16 + (l & 15);
        Wl3sF[t] = f2bf(Wl3s[k * 64 + n]);
        return;
    }
    t -= 6144;
    if (t < 3072) {
        int i = t & 7, l = (t >> 3) & 63, rem = t >> 9;
        int ks = rem % 3, nt = rem / 3;
        int k = ks * 32 + ((l >> 4) << 3) + i;
        int n = nt * 16 + (l & 15);
        Wl3vF[t] = f2bf(Wl3v[k * 32 + n]);
        return;
    }
    t -= 3072;
    if (t < 8192) {
        int i = t & 7, l = (t >> 3) & 63, rem = t >> 9;
        int ks = rem & 3, nt = rem >> 2;
        int k = ks * 32 + ((l >> 4) << 3) + i;
        int n = nt * 16 + (l & 15);
        WscF[t] = f2bf(k < 64 ? Wsa[k * 64 + n] : Wsc[(k - 64) * 64 + n]);
        return;
    }
    t -= 8192;
    if (t < 8192) {
        int i = t & 7, l = (t >> 3) & 63, rem = t >> 9;
        int ks = rem & 3, nt = rem >> 2;
        int k = ks * 32 + ((l >> 4) << 3) + i;
        int n = nt * 16 + (l & 15);
        W1sF[t] = f2bf(k < 64 ? W1sa[k * 64 + n] : W1sc[(k - 64) * 64 + n]);
        return;
    }
    t -= 8192;
    if (t < 2048) {
        int i = t & 7, l = (t >> 3) & 63, rem = t >> 9;
        int ks = rem & 1, nt = rem >> 1;
        int k = ks * 32 + ((l >> 4) << 3) + i;
        int n = nt * 16 + (l & 15);
        WvcF[t] = f2bf(k < 32 ? Wva[k * 32 + n] : Wvc[(k - 32) * 32 + n]);
        return;
    }
    t -= 2048;
    if (t < 2048) {
        int i = t & 7, l = (t >> 3) & 63, rem = t >> 9;
        int ks = rem & 1, nt = rem >> 1;
        int k = ks * 32 + ((l >> 4) << 3) + i;
        int n = nt * 16 + (l & 15);
        W1vF[t] = f2bf(k < 32 ? W1va[k * 32 + n] : W1vc[(k - 32) * 32 + n]);
        return;
    }
}

// ---------------- K1: node prep via MFMA ---------------------------------------
__global__ __launch_bounds__(256, 2) void k_np_mfma(
    const float* __restrict__ ni, const float* __restrict__ attr, const float* __restrict__ cattr,
    const unsigned short* __restrict__ WscF, const unsigned short* __restrict__ W1sF,
    const unsigned short* __restrict__ WvcF, const unsigned short* __restrict__ W1vF,
    float* __restrict__ x1, float* __restrict__ out)
{
    __shared__ char A1[64 * 256];
    int slot = blockIdx.y, cc = slot - 1;
    int n0 = blockIdx.x * 64;
    int tid = threadIdx.x, lane = tid & 63, w = tid >> 6;

    if (slot == 0) {
        for (int idx = tid; idx < 64 * 64; idx += 256) {
            int r = idx >> 6, k = idx & 63;
            int n = n0 + r;
            float a = 0.f, cv = 0.f, val = 0.f;
            if (n < NN) { a = attr[n]; cv = cattr[n]; val = ni[(size_t)n * 160 + k]; }
            int sw = (r & 7) << 4;
            *(unsigned short*)(A1 + r * 256 + ((2 * k) ^ sw))       = f2bf(a  * val);
            *(unsigned short*)(A1 + r * 256 + ((128 + 2 * k) ^ sw)) = f2bf(cv * val);
        }
    } else {
        for (int idx = tid; idx < 64 * 32; idx += 256) {
            int r = idx >> 5, u = idx & 31;
            int n = n0 + r;
            float a = 0.f, cv = 0.f, val = 0.f;
            if (n < NN) { a = attr[n]; cv = cattr[n]; val = ni[(size_t)n * 160 + 64 + 3 * u + cc]; }
            int sw = (r & 7) << 4;
            *(unsigned short*)(A1 + r * 128 + ((2 * u) ^ sw))      = f2bf(a  * val);
            *(unsigned short*)(A1 + r * 128 + ((64 + 2 * u) ^ sw)) = f2bf(cv * val);
        }
    }
    __syncthreads();

    int arow = w * 16 + (lane & 15);
    int asw  = (arow & 7) << 4;

    if (slot == 0) {
        f32x4 accS[4], accX[4];
        #pragma unroll
        for (int nt = 0; nt < 4; ++nt) { accS[nt] = (f32x4)0.f; accX[nt] = (f32x4)0.f; }
        #pragma unroll
        for (int ks = 0; ks < 4; ++ks) {
            int kb = ks * 64 + ((lane >> 4) << 4);
            bf16x8 af = *(const bf16x8*)(A1 + arow * 256 + (kb ^ asw));
            #pragma unroll
            for (int nt = 0; nt < 4; ++nt) {
                bf16x8 b1 = *(const bf16x8*)(WscF + (size_t)(((nt * 4 + ks) * 64) + lane) * 8);
                bf16x8 b2 = *(const bf16x8*)(W1sF + (size_t)(((nt * 4 + ks) * 64) + lane) * 8);
                accS[nt] = __builtin_amdgcn_mfma_f32_16x16x32_bf16(af, b1, accS[nt], 0, 0, 0);
                accX[nt] = __builtin_amdgcn_mfma_f32_16x16x32_bf16(af, b2, accX[nt], 0, 0, 0);
            }
        }
        #pragma unroll
        for (int r = 0; r < 4; ++r) {
            int n = n0 + w * 16 + ((lane >> 4) << 2) + r;
            if (n >= NN) continue;
            #pragma unroll
            for (int nt = 0; nt < 4; ++nt) {
                int col = nt * 16 + (lane & 15);
                out[(size_t)n * 160 + col] = C_S_ * accS[nt][r];
                x1[(size_t)n * 160 + col]  = accX[nt][r];
            }
        }
    } else {
        f32x4 accS[2], accX[2];
        #pragma unroll
        for (int nt = 0; nt < 2; ++nt) { accS[nt] = (f32x4)0.f; accX[nt] = (f32x4)0.f; }
        #pragma unroll
        for (int ks = 0; ks < 2; ++ks) {
            int kb = ks * 64 + ((lane >> 4) << 4);
            bf16x8 af = *(const bf16x8*)(A1 + arow * 128 + (kb ^ asw));
            #pragma unroll
            for (int nt = 0; nt < 2; ++nt) {
                bf16x8 b1 = *(const bf16x8*)(WvcF + (size_t)(((nt * 2 + ks) * 64) + lane) * 8);
                bf16x8 b2 = *(const bf16x8*)(W1vF + (size_t)(((nt * 2 + ks) * 64) + lane) * 8);
                accS[nt] = __builtin_amdgcn_mfma_f32_16x16x32_bf16(af, b1, accS[nt], 0, 0, 0);
                accX[nt] = __builtin_amdgcn_mfma_f32_16x16x32_bf16(af, b2, accX[nt], 0, 0, 0);
            }
        }
        #pragma unroll
        for (int r = 0; r < 4; ++r) {
            int n = n0 + w * 16 + ((lane >> 4) << 2) + r;
            if (n >= NN) continue;
            #pragma unroll
            for (int nt = 0; nt < 2; ++nt) {
                int o = nt * 16 + (lane & 15);
                int d = 64 + 3 * o + cc;
                out[(size_t)n * 160 + d] = C_S_ * accS[nt][r];
                x1[(size_t)n * 160 + d]  = accX[nt][r];
            }
        }
    }
}

// ---------------- sort: histogram ---------------------------------------------
__global__ __launch_bounds__(256) void k_hist(const int* __restrict__ edst, int* __restrict__ cnt) {
    int e = blockIdx.x * blockDim.x + threadIdx.x;
    if (e >= NE) return;
    atomicAdd(&cnt[edst[e]], 1);
}

// ---------------- sort: single-block exclusive scan over NN counts ------------
__global__ __launch_bounds__(1024) void k_scan(const int* __restrict__ cnt,
                                               int* __restrict__ start, int* __restrict__ cursor) {
    __shared__ int wsum[16];
    __shared__ int carry_s;
    int lane = threadIdx.x & 63, wid = threadIdx.x >> 6;
    if (threadIdx.x == 0) carry_s = 0;
    __syncthreads();
    for (int base = 0; base < NN; base += 1024) {
        int i = base + threadIdx.x;
        int v = (i < NN) ? cnt[i] : 0;
        int x = v;
        #pragma unroll
        for (int off = 1; off < 64; off <<= 1) {
            int y = __shfl_up(x, off, 64);
            if (lane >= off) x += y;
        }
        if (lane == 63) wsum[wid] = x;
        __syncthreads();
        if (wid == 0 && lane < 16) {
            int s = wsum[lane];
            #pragma unroll
            for (int off = 1; off < 16; off <<= 1) {
                int y = __shfl_up(s, off, 64);
                if (lane >= off) s += y;
            }
            wsum[lane] = s;
        }
        __syncthreads();
        int woff = (wid > 0) ? wsum[wid - 1] : 0;
        int excl = x - v + woff + carry_s;
        if (i < NN) { start[i] = excl; cursor[i] = excl; }
        __syncthreads();
        if (threadIdx.x == 1023) carry_s += wsum[15];
        __syncthreads();
    }
    if (threadIdx.x == 0) start[NN] = NE;
}

// ---------------- sort: scatter — permute ele/esrc/eattr/ndst into sorted order
__global__ __launch_bounds__(256) void k_scatter(const int* __restrict__ edst,
                                                 const int* __restrict__ esrc,
                                                 const float* __restrict__ eattr,
                                                 const float* __restrict__ ele,
                                                 int* __restrict__ cursor,
                                                 int* __restrict__ esrc_s,
                                                 int* __restrict__ ndst_s,
                                                 float4* __restrict__ eattr_s,
                                                 float* __restrict__ ele_s) {
    int e = blockIdx.x * blockDim.x + threadIdx.x;
    if (e >= NE) return;
    int dst = edst[e];
    int p = atomicAdd(&cursor[dst], 1);
    esrc_s[p]  = esrc[e];
    ndst_s[p]  = dst;
    eattr_s[p] = *(const float4*)(eattr + (size_t)e * 4);
    #pragma unroll
    for (int k = 0; k < 10; ++k) ele_s[(size_t)p * 10 + k] = ele[(size_t)e * 10 + k];
}

// ---------------- K2: FUSED edge MLP + MFMA + tensor-product aggregation -------
// Block = 64 sorted edges, 384 threads (6 waves). hA/wS share LDS (~30 KB).
// Phase 5 v3 + 8-deep gather batching (R11 evidence: deeper in-flight x1 loads).
__global__ __launch_bounds__(384, 8) void k_fused(
    const float* __restrict__ ele_s, const int* __restrict__ esrc_s,
    const int* __restrict__ ndst_s, const float4* __restrict__ eattr_s,
    const int* __restrict__ start,
    const float* __restrict__ Wfc1, const unsigned short* __restrict__ Wfragb,
    const float* __restrict__ x1, float* __restrict__ agg,
    float* __restrict__ partials, int* __restrict__ pnid)
{
    __shared__ float  els[640];
    __shared__ int    nid[64];
    __shared__ unsigned long long bmask_s;
    __shared__ char   uS[64 * (WSP * 2)];    // phase2-3: hA [64][256B]; phase4-5: wS [64][WSP shorts]
    char* hA = uS;
    unsigned short* wS = (unsigned short*)uS;

    int tid = threadIdx.x, lane = tid & 63, w = tid >> 6;
    int b = blockIdx.x;
    int base = b * 64;

    // phase 1: stage per-edge data consumed per-lane (els) / per-flush (nid)
    for (int idx = tid; idx < 640; idx += 384) els[idx] = ele_s[(size_t)base * 10 + idx];
    if (tid < 64) nid[tid] = ndst_s[base + tid];
    if (tid == 0) { pnid[b * 2 + 0] = -1; pnid[b * 2 + 1] = -1; }
    __syncthreads();

    // phase 2: h = silu(el @ Wfc1) -> hA (row-major map: conflict-free writes)
    #pragma unroll 1
    for (int t2 = tid; t2 < 6400; t2 += 384) {
        int e_loc = t2 / 100;
        int j = t2 - e_loc * 100;
        const float* elp = els + e_loc * 10;
        float acc = 0.f;
        #pragma unroll
        for (int k = 0; k < 10; ++k) acc += elp[k] * Wfc1[k * 100 + j];
        float hv = acc / (1.f + __expf(-acc));
        *(unsigned short*)(hA + e_loc * 256 + ((j * 2) ^ ((e_loc & 7) << 4))) = f2bf(hv);
    }
    for (int idx = tid; idx < 64 * 28; idx += 384) {
        int e_loc = idx / 28;
        int col2 = (100 + (idx - e_loc * 28)) * 2;
        *(unsigned short*)(hA + e_loc * 256 + (col2 ^ ((e_loc & 7) << 4))) = 0;
    }
    __syncthreads();

    // phase 3: MFMA — 6 waves x 2 n-tiles x 4 mt x 4 ks
    bf16x8 bfr[2][4];
    #pragma unroll
    for (int nt2 = 0; nt2 < 2; ++nt2)
        #pragma unroll
        for (int ks = 0; ks < 4; ++ks)
            bfr[nt2][ks] = ((const bf16x8*)Wfragb)[(((w * 2 + nt2) * 4) + ks) * 64 + lane];

    f32x4 acc[4][2];
    #pragma unroll
    for (int mt = 0; mt < 4; ++mt)
        #pragma unroll
        for (int nt2 = 0; nt2 < 2; ++nt2)
            acc[mt][nt2] = (f32x4)0.f;

    #pragma unroll
    for (int mt = 0; mt < 4; ++mt) {
        int row = mt * 16 + (lane & 15);
        #pragma unroll
        for (int ks = 0; ks < 4; ++ks) {
            int kb = ks * 64 + ((lane >> 4) << 4);
            bf16x8 a = *(const bf16x8*)(hA + row * 256 + (kb ^ ((row & 7) << 4)));
            #pragma unroll
            for (int nt2 = 0; nt2 < 2; ++nt2)
                acc[mt][nt2] = __builtin_amdgcn_mfma_f32_16x16x32_bf16(a, bfr[nt2][ks], acc[mt][nt2], 0, 0, 0);
        }
    }
    __syncthreads();   // hA dead; wS aliases it — all reads must complete first

    // phase 4: weights -> LDS, pitch WSP=204 (4-row groups hit disjoint banks)
    #pragma unroll
    for (int mt = 0; mt < 4; ++mt) {
        #pragma unroll
        for (int nt2 = 0; nt2 < 2; ++nt2) {
            int col = (w * 2 + nt2) * 16 + (lane & 15);
            #pragma unroll
            for (int r = 0; r < 4; ++r) {
                int row = mt * 16 + ((lane >> 4) << 2) + r;
                wS[row * WSP + col] = f2bf(acc[mt][nt2][r]);
            }
        }
    }
    // segment-boundary bitmask (wave 0); published by the same barrier as wS
    if (tid < 64) {
        bool lastb = (tid == 63) || (nid[tid + 1] != nid[tid]);
        unsigned long long m = __ballot(lastb);
        if (tid == 0) bmask_s = m;
    }
    __syncthreads();   // RAW fence for wS + bmask_s (R9 lesson)

    // phase 5 v3 + depth-8: 192 active threads; triples share the common factor.
    int t = tid;
    if (t < 192) {
        int role, widx, gidx, dcol;
        float scale;
        if (t < 64)       { role = 0; widx = t;       gidx = t;           dcol = t;           scale = Q_;   }
        else if (t < 96)  { int o = t - 64;  role = 1; widx = 160 + o; gidx = 64 + 3 * o; dcol = 64 + o;      scale = Q_S3; }
        else if (t < 160) { int u = t - 96;  role = 2; widx = 64 + u;  gidx = u;          dcol = 96 + 3 * u;  scale = Q_;   }
        else              { int o = t - 160; role = 3; widx = 128 + o; gidx = 64 + 3 * o; dcol = 288 + 3 * o; scale = Q_;   }
        bool needs3g = (role == 1) || (role == 3);

        unsigned long long bm = bmask_s;
        float a0 = 0.f, a1 = 0.f, a2 = 0.f;
        int curNode = nid[0];
        int firstNode = curNode;
        #pragma unroll 1
        for (int i0 = 0; i0 < 64; i0 += 8) {
            float g0[8], g1[8], g2[8];
            #pragma unroll
            for (int q = 0; q < 8; ++q) {
                const float* g = x1 + (size_t)esrc_s[base + i0 + q] * 160;
                g0[q] = g[gidx];
                if (needs3g) { g1[q] = g[gidx + 1]; g2[q] = g[gidx + 2]; }
            }
            #pragma unroll
            for (int q = 0; q < 8; ++q) {
                int i = i0 + q;
                float4 ea = eattr_s[base + i];
                float wv = bf2f(wS[i * WSP + widx]);
                if (role == 0)      a0 += wv * g0[q] * ea.x;
                else if (role == 1) a0 += wv * (g0[q] * ea.y + g1[q] * ea.z + g2[q] * ea.w);
                else if (role == 2) { float p = wv * g0[q]; a0 += p * ea.y; a1 += p * ea.z; a2 += p * ea.w; }
                else                { float p = wv * ea.x;  a0 += p * g0[q]; a1 += p * g1[q]; a2 += p * g2[q]; }
                if ((bm >> i) & 1ull) {
                    int n = curNode;
                    int s0n = start[n], s1n = start[n + 1];
                    bool interior = (s0n >= base) && (s1n <= base + 64);
                    float* dstp;
                    if (interior) {
                        dstp = agg + (size_t)n * 384;
                    } else if (n == firstNode) {
                        dstp = partials + ((size_t)b * 2 + 0) * 384;
                        if (t == 0) pnid[b * 2 + 0] = n;
                    } else {
                        dstp = partials + ((size_t)b * 2 + 1) * 384;
                        if (t == 0) pnid[b * 2 + 1] = n;
                    }
                    dstp[dcol] = a0 * scale;
                    if (role >= 2) { dstp[dcol + 1] = a1 * scale; dstp[dcol + 2] = a2 * scale; }
                    a0 = a1 = a2 = 0.f;
                    if (i < 63) curNode = nid[i + 1];
                }
            }
        }
    }
}

// ---------------- K2c: fixup — sum partials for block-spanning nodes ----------
__global__ __launch_bounds__(256) void k_fixup(
    const int* __restrict__ start, const int* __restrict__ pnid,
    const float* __restrict__ partials, float* __restrict__ agg)
{
    int T = blockIdx.x * blockDim.x + threadIdx.x;
    if (T >= NN * 384) return;
    int n = T / 384, col = T - n * 384;
    int s0 = start[n], s1 = start[n + 1];
    if (s0 == s1) { agg[(size_t)n * 384 + col] = 0.f; return; }
    int b0 = s0 >> 6, b1 = (s1 - 1) >> 6;
    if (b0 == b1) return;   // interior: direct-written by k_fused
    float sum = 0.f;
    for (int b = b0; b <= b1; ++b) {
        if (pnid[2 * b]     == n) sum += partials[((size_t)2 * b)     * 384 + col];
        if (pnid[2 * b + 1] == n) sum += partials[((size_t)2 * b + 1) * 384 + col];
    }
    agg[(size_t)n * 384 + col] = sum;
}

// ---------------- K3: fused l2+l3 double-MFMA ---------------------------------
__global__ __launch_bounds__(256, 2) void k_l23(
    const float* __restrict__ agg, const float* __restrict__ attr,
    const float* __restrict__ cattr, const float* __restrict__ sym,
    const unsigned short* __restrict__ WsabF, const unsigned short* __restrict__ WvabF,
    const unsigned short* __restrict__ Wl3sF, const unsigned short* __restrict__ Wl3vF,
    float* __restrict__ out)
{
    __shared__ char A1[64 * 512];
    __shared__ char A2[64 * 256];

    int slot = blockIdx.y;
    int cc   = slot - 1;
    int n0   = blockIdx.x * 64;
    int tid  = threadIdx.x, lane = tid & 63, w = tid >> 6;

    for (int idx = tid; idx < 64 * 96; idx += 256) {
        int r = idx / 96, km = idx - r * 96;
        int n = n0 + r;
        float a = 0.f, cv = 0.f, val = 0.f;
        if (n < NN) {
            a = attr[n]; cv = cattr[n];
            int src = (slot == 0) ? km : (96 + 3 * km + cc);
            val = agg[(size_t)n * 384 + src];
        }
        int sw = (r & 7) << 4;
        *(unsigned short*)(A1 + r * 512 + ((2 * km) ^ sw))         = f2bf(a  * val);
        *(unsigned short*)(A1 + r * 512 + ((192 + 2 * km) ^ sw))   = f2bf(cv * val);
    }
    __syncthreads();

    const unsigned short* Bf = (slot == 0) ? WsabF : WvabF;
    f32x4 acc1[6];
    #pragma unroll
    for (int nt = 0; nt < 6; ++nt) acc1[nt] = (f32x4)0.f;

    int arow = w * 16 + (lane & 15);
    int asw  = (arow & 7) << 4;
    #pragma unroll
    for (int ks = 0; ks < 6; ++ks) {
        int kb = ks * 64 + ((lane >> 4) << 4);
        bf16x8 af = *(const bf16x8*)(A1 + arow * 512 + (kb ^ asw));
        #pragma unroll
        for (int nt = 0; nt < 6; ++nt) {
            bf16x8 bfrag = *(const bf16x8*)(Bf + (size_t)(((nt * 6 + ks) * 64) + lane) * 8);
            acc1[nt] = __builtin_amdgcn_mfma_f32_16x16x32_bf16(af, bfrag, acc1[nt], 0, 0, 0);
        }
    }

    #pragma unroll
    for (int nt = 0; nt < 6; ++nt) {
        int ncol2 = (nt * 16 + (lane & 15)) * 2;
        #pragma unroll
        for (int r = 0; r < 4; ++r) {
            int row = w * 16 + ((lane >> 4) << 2) + r;
            *(unsigned short*)(A2 + row * 256 + (ncol2 ^ ((row & 7) << 4))) = f2bf(acc1[nt][r]);
        }
    }

    __syncthreads();   // RAW fence (R9 lesson)

    int NT2 = (slot == 0) ? 4 : 2;
    const unsigned short* B2 = (slot == 0) ? Wl3sF : Wl3vF;
    f32x4 acc2[4];
    #pragma unroll
    for (int nt2 = 0; nt2 < 4; ++nt2) acc2[nt2] = (f32x4)0.f;

    #pragma unroll
    for (int ks = 0; ks < 3; ++ks) {
        int kb = ks * 64 + ((lane >> 4) << 4);
        bf16x8 a2 = *(const bf16x8*)(A2 + arow * 256 + (kb ^ ((arow & 7) << 4)));
        #pragma unroll
        for (int nt2 = 0; nt2 < 4; ++nt2) {
            if (nt2 < NT2) {
                bf16x8 b2 = *(const bf16x8*)(B2 + (size_t)(((nt2 * 3 + ks) * 64) + lane) * 8);
                acc2[nt2] = __builtin_amdgcn_mfma_f32_16x16x32_bf16(a2, b2, acc2[nt2], 0, 0, 0);
            }
        }
    }

    #pragma unroll
    for (int r = 0; r < 4; ++r) {
        int n = n0 + w * 16 + ((lane >> 4) << 2) + r;
        if (n >= NN) continue;
        float sv = C_X_ * sym[n];
        #pragma unroll
        for (int nt2 = 0; nt2 < 4; ++nt2) {
            if (nt2 < NT2) {
                int col = nt2 * 16 + (lane & 15);
                int d = (slot == 0) ? col : (64 + 3 * col + cc);
                out[(size_t)n * 160 + d] += sv * acc2[nt2][r];
            }
        }
    }
}

extern "C" void kernel_launch(void* const* d_in, const int* in_sizes, int n_in,
                              void* d_out, int out_size, void* d_ws, size_t ws_size,
                              hipStream_t stream) {
    const float* ni    = (const float*)d_in[0];
    const float* attr  = (const float*)d_in[1];
    const float* cattr = (const float*)d_in[2];
    const float* sym   = (const float*)d_in[3];
    const float* eattr = (const float*)d_in[4];
    const float* ele   = (const float*)d_in[5];
    const int*   esrc  = (const int*)d_in[6];
    const int*   edst  = (const int*)d_in[7];
    const float* Ws_sc_a = (const float*)d_in[8];
    const float* Wv_sc_a = (const float*)d_in[9];
    const float* Ws_sc_c = (const float*)d_in[10];
    const float* Wv_sc_c = (const float*)d_in[11];
    const float* Ws_l1_a = (const float*)d_in[12];
    const float* Wv_l1_a = (const float*)d_in[13];
    const float* Ws_l1_c = (const float*)d_in[14];
    const float* Wv_l1_c = (const float*)d_in[15];
    const float* Wfc1    = (const float*)d_in[16];
    const float* Wfc2    = (const float*)d_in[17];
    const float* Ws_l2_a = (const float*)d_in[18];
    const float* Wv_l2_a = (const float*)d_in[19];
    const float* Ws_l2_c = (const float*)d_in[20];
    const float* Wv_l2_c = (const float*)d_in[21];
    const float* Ws_l3   = (const float*)d_in[22];
    const float* Wv_l3   = (const float*)d_in[23];

    float* out = (float*)d_out;
    float* ws  = (float*)d_ws;
    float* x1  = ws;                          // NN*160 f32
    float* agg = x1 + (size_t)NN * 160;       // NN*384 f32
    unsigned short* Wfragb = (unsigned short*)(agg + (size_t)NN * 384);  // 24576
    unsigned short* WsabF  = Wfragb + 24576;                 // 18432
    unsigned short* WvabF  = WsabF + 18432;                  // 18432
    unsigned short* Wl3sF  = WvabF + 18432;                  // 6144
    unsigned short* Wl3vF  = Wl3sF + 6144;                   // 3072
    unsigned short* WscF   = Wl3vF + 3072;                   // 8192
    unsigned short* W1sF   = WscF + 8192;                    // 8192
    unsigned short* WvcF   = W1sF + 8192;                    // 2048
    unsigned short* W1vF   = WvcF + 2048;                    // 2048
    float4* eattr_s = (float4*)(W1vF + 2048);                // NE float4
    float*  ele_s   = (float*)(eattr_s + NE);                // NE*10 f32
    int* esrc_s  = (int*)(ele_s + (size_t)NE * 10);          // NE
    int* ndst_s  = esrc_s + NE;                              // NE
    int* cnt     = ndst_s + NE;                              // NN
    int* start_  = cnt + NN;                                 // NN+1
    int* cursor  = start_ + NN + 1;                          // NN
    int* pnid    = cursor + NN;                              // 2*NB_
    float* partials = (float*)(pnid + 2 * NB_);              // 2*NB_*384 f32

    size_t need = ((size_t)NN * 160 + (size_t)NN * 384) * 4
                + (size_t)91136 * 2
                + (size_t)NE * 16 + (size_t)NE * 10 * 4
                + ((size_t)NE * 2 + (size_t)NN * 3 + 1 + 2 * NB_) * 4
                + (size_t)2 * NB_ * 384 * 4;
    if (ws_size < need) return;

    k_pack<<<(91136 + 255) / 256, 256, 0, stream>>>(
        Wfc2,
        Ws_sc_a, Ws_sc_c, Ws_l1_a, Ws_l1_c,
        Wv_sc_a, Wv_sc_c, Wv_l1_a, Wv_l1_c,
        Ws_l2_a, Ws_l2_c, Wv_l2_a, Wv_l2_c,
        Ws_l3, Wv_l3,
        Wfragb, WsabF, WvabF, Wl3sF, Wl3vF,
        WscF, W1sF, WvcF, W1vF);

    k_np_mfma<<<dim3((NN + 63) / 64, 4), 256, 0, stream>>>(
        ni, attr, cattr, WscF, W1sF, WvcF, W1vF, x1, out);

    hipMemsetAsync(cnt, 0, (size_t)NN * sizeof(int), stream);
    k_hist<<<(NE + 255) / 256, 256, 0, stream>>>(edst, cnt);
    k_scan<<<1, 1024, 0, stream>>>(cnt, start_, cursor);
    k_scatter<<<(NE + 255) / 256, 256, 0, stream>>>(
        edst, esrc, eattr, ele, cursor, esrc_s, ndst_s, eattr_s, ele_s);

    k_fused<<<NB_, 384, 0, stream>>>(
        ele_s, esrc_s, ndst_s, eattr_s, start_,
        Wfc1, Wfragb, x1, agg, partials, pnid);

    k_fixup<<<(NN * 384 + 255) / 256, 256, 0, stream>>>(
        start_, pnid, partials, agg);

    k_l23<<<dim3((NN + 63) / 64, 4), 256, 0, stream>>>(
        agg, attr, cattr, sym, WsabF, WvabF, Wl3sF, Wl3vF, out);
}